// Round 1
// baseline (16132.796 us; speedup 1.0000x reference)
//
#include <hip/hip_runtime.h>
#include <stdint.h>

// ---------------- problem constants ----------------
#define HDIM   1024
#define BATCH  128
#define TENC   256
#define TDEC   128
#define NSTEPS 384      // 256 encoder + 128 decoder timesteps
#define PITCH0 2176     // LDS row pitch for layer0 A-tile (K=1056 + XOR pad window)
#define PITCH1 4096     // LDS row pitch for layer1 A-tile (K=2048)

typedef __attribute__((ext_vector_type(8))) short s16x8;
typedef __attribute__((ext_vector_type(4))) float f32x4;

// ---------------- workspace layout (bytes) ----------------
#define OFF_XBF 0u         // x as bf16 [128][256][8]            512 KB
#define OFF_YBF 524288u    // y as bf16 [128][128]                32 KB
#define OFF_H0  557056u    // h0 state  [2 parity][128][1024] bf16, u-swizzled  512 KB
#define OFF_H1  1081344u   // h1 state  same                                  512 KB
#define OFF_MU  1605632u   // mu  partial accum [128 t][128 b] f32             64 KB
#define OFF_SIG 1671168u   // sig partial accum                                64 KB
#define OFF_BAR 1736704u   // barrier counters: 4 groups x 4 slots x 256B       4 KB
#define WS_END  1740800u

__device__ __forceinline__ unsigned short f2bf(float f) {   // f32 -> bf16 RNE
  unsigned u = __float_as_uint(f);
  u = u + 0x7fffu + ((u >> 16) & 1u);
  return (unsigned short)(u >> 16);
}
__device__ __forceinline__ float sigm(float x) { return 1.f / (1.f + __expf(-x)); }
__device__ __forceinline__ float tanh_f(float x) {
  float a = fabsf(x);
  float e = __expf(-2.f * a);          // in (0,1], no overflow
  float t = (1.f - e) / (1.f + e);
  return x < 0.f ? -t : t;
}

// async global->LDS, 16B per lane; LDS dest is wave-uniform base + lane*16
__device__ __forceinline__ void glds16(const void* g, void* l) {
  __builtin_amdgcn_global_load_lds((const __attribute__((address_space(1))) void*)g,
                                   (__attribute__((address_space(3))) void*)l,
                                   16, 0, 0);
}

// -------- resident-weight loader (bf16 MFMA B-frags, K-split stride-4 over waves) --------
// layer0: wfa[j][gate], j -> kst = w+4j (9 slots; kst==32 is the x/y slot, kst>32 zero pad)
// layer1: wfb[j][gate], j -> kst = w+4j (16 slots; kst<32 -> Wih1 (h0 part), else Whh1)
__device__ __forceinline__ void load_weights(
    s16x8 (&wfa)[9][4], s16x8 (&wfb)[16][4],
    int w, int u0, int l15, int khi,
    const float* W0h, const float* W0x, int xk,
    const float* W1x, const float* W1h) {
#pragma unroll
  for (int j = 0; j < 9; ++j) {
    int kst = w + 4 * j;
#pragma unroll
    for (int n = 0; n < 4; ++n) {
      int g = n * 1024 + u0 + l15;          // global gate row (torch order i,f,g,o)
      s16x8 v;
#pragma unroll
      for (int e = 0; e < 8; ++e) ((unsigned short*)&v)[e] = 0;
      if (kst < 32) {
        const float* p = W0h + (size_t)g * 1024 + kst * 32 + khi * 8;
#pragma unroll
        for (int e = 0; e < 8; ++e) ((unsigned short*)&v)[e] = f2bf(p[e]);
      } else if (kst == 32) {
        if (khi == 0) {
#pragma unroll
          for (int e = 0; e < 8; ++e)
            if (e < xk) ((unsigned short*)&v)[e] = f2bf(W0x[(size_t)g * xk + e]);
        }
      }
      wfa[j][n] = v;
    }
  }
#pragma unroll
  for (int j = 0; j < 16; ++j) {
    int kst = w + 4 * j;
#pragma unroll
    for (int n = 0; n < 4; ++n) {
      int g = n * 1024 + u0 + l15;
      const float* p = (kst < 32)
          ? (W1x + (size_t)g * 1024 + kst * 32 + khi * 8)
          : (W1h + (size_t)g * 1024 + (kst - 32) * 32 + khi * 8);
      s16x8 v;
#pragma unroll
      for (int e = 0; e < 8; ++e) ((unsigned short*)&v)[e] = f2bf(p[e]);
      wfb[j][n] = v;
    }
  }
}

// ---------------- input conversion ----------------
__global__ void cvt_inputs(const float* __restrict__ x, const float* __restrict__ y,
                           unsigned short* __restrict__ xbf, unsigned short* __restrict__ ybf) {
  int i = blockIdx.x * 256 + threadIdx.x;
  if (i < 262144) xbf[i] = f2bf(x[i]);                 // [b][t][k] flat
  if (i < 16384) {
    int b = i >> 7, t = i & 127;
    ybf[i] = f2bf(y[b * 129 + t]);                     // y[:, :128]
  }
}

// ---------------- main persistent kernel ----------------
__global__ void __launch_bounds__(256, 1) lstm_main(
    const float* __restrict__ eWx0, const float* __restrict__ eWh0,
    const float* __restrict__ eB0a, const float* __restrict__ eB0b,
    const float* __restrict__ eWx1, const float* __restrict__ eWh1,
    const float* __restrict__ eB1a, const float* __restrict__ eB1b,
    const float* __restrict__ dWx0, const float* __restrict__ dWh0,
    const float* __restrict__ dB0a, const float* __restrict__ dB0b,
    const float* __restrict__ dWx1, const float* __restrict__ dWh1,
    const float* __restrict__ dB1a, const float* __restrict__ dB1b,
    const float* __restrict__ Wmu, const float* __restrict__ Wsig,
    const unsigned short* __restrict__ xbf, const unsigned short* __restrict__ ybf,
    unsigned short* h0buf, unsigned short* h1buf,
    float* mu_acc, float* sig_acc, unsigned* bars) {
  __shared__ char smem[131072];   // A-tile (<=128KB); first 32KB overlaid as f32 exchange buffer
  float* ex = (float*)smem;       // ex[wave][row32][col64]

  const int tid = threadIdx.x;
  const int wg = blockIdx.x;
  const int w = tid >> 6;          // wave 0..3 (K-split)
  const int lane = tid & 63;
  const int l15 = lane & 15;
  const int khi = lane >> 4;       // k sub-slice 0..3 (8 elems each)
  const int btile = wg & 3;        // batch tile (also sync group; XCD-friendly: wg%8 fixes wg%4)
  const int utile = wg >> 2;       // 0..63 -> 16 hidden units
  const int u0 = utile << 4;
  const int r0 = btile << 5;       // 32 batch rows
  const int key = (l15 & 7) << 4;  // XOR bank swizzle key (row&7 == l15&7 for our tiles)

  unsigned* cnt1 = bars + btile * 256;
  unsigned* rel1 = bars + btile * 256 + 64;
  unsigned* cnt2 = bars + btile * 256 + 128;
  unsigned* rel2 = bars + btile * 256 + 192;

  s16x8 wfa[9][4];
  s16x8 wfb[16][4];
  load_weights(wfa, wfb, w, u0, l15, khi, eWh0, eWx0, 8, eWx1, eWh1);
  const float* pB0a = eB0a; const float* pB0b = eB0b;
  const float* pB1a = eB1a; const float* pB1b = eB1b;

  // per-thread persistent cell state: elementwise partition (erow, 2 units)
  const int erow = tid >> 3;            // 0..31
  const int euu = (tid & 7) << 1;       // 0,2,..,14
  const int eb = r0 + erow;
  float c0reg0 = 0.f, c0reg1 = 0.f, c1reg0 = 0.f, c1reg1 = 0.f;

  for (int s = 0; s < NSTEPS; ++s) {
    if (s == 256) {   // encoder -> decoder: reload resident weights/biases once
      load_weights(wfa, wfb, w, u0, l15, khi, dWh0, dWx0, 1, dWx1, dWh1);
      pB0a = dB0a; pB0b = dB0b; pB1a = dB1a; pB1b = dB1b;
    }
    const int enc = (s < 256) ? 1 : 0;
    const int t = enc ? s : (s - 256);
    const int par = s & 1;

    // ===================== LAYER 0 sub-step =====================
    {
      // stage A0: rows of h0[par] (pre-swizzled in global -> linear copy) + x/y K-slot
#pragma unroll
      for (int rr = 0; rr < 8; ++rr) {
        int row = w * 8 + rr;
        const char* src = (const char*)(h0buf + ((size_t)(par * BATCH + r0 + row) << 10));
        char* dst = smem + row * PITCH0;
        glds16(src + lane * 16, dst);
        glds16(src + 1024 + lane * 16, dst + 1024);
      }
      if (tid < 32) {
        int row = tid;
        char* wb = smem + row * PITCH0 + 2048;
        s16x8 z;
#pragma unroll
        for (int e = 0; e < 8; ++e) ((unsigned short*)&z)[e] = 0;
#pragma unroll
        for (int q = 0; q < 8; ++q) *(s16x8*)(wb + q * 16) = z;   // zero XOR window
        int slot = (row & 7) << 4;
        if (enc) {
          *(s16x8*)(wb + slot) = *(const s16x8*)(xbf + (((size_t)(r0 + row) * TENC + t) << 3));
        } else {
          s16x8 yv = z;
          ((unsigned short*)&yv)[0] = ybf[(r0 + row) * TDEC + t];
          *(s16x8*)(wb + slot) = yv;
        }
      }
      asm volatile("s_waitcnt vmcnt(0)" ::: "memory");
      __syncthreads();

      // MFMA: wave w does kst = w+4j; kst>32 uses zero W-frag (safe A read at off 0)
      f32x4 acc[2][4];
#pragma unroll
      for (int m = 0; m < 2; ++m)
#pragma unroll
        for (int n = 0; n < 4; ++n) acc[m][n] = {0.f, 0.f, 0.f, 0.f};
#pragma unroll
      for (int j = 0; j < 9; ++j) {
        int kst = w + 4 * j;
        int off = (kst > 32) ? 0 : (kst << 6);
#pragma unroll
        for (int m = 0; m < 2; ++m) {
          const s16x8 af = *(const s16x8*)(smem + (m * 16 + l15) * PITCH0 + ((off + khi * 16) ^ key));
#pragma unroll
          for (int n = 0; n < 4; ++n)
            acc[m][n] = __builtin_amdgcn_mfma_f32_16x16x32_bf16(af, wfa[j][n], acc[m][n], 0, 0, 0);
        }
      }
      __syncthreads();   // all A reads done before ex overlay
#pragma unroll
      for (int m = 0; m < 2; ++m)
#pragma unroll
        for (int n = 0; n < 4; ++n)
#pragma unroll
          for (int r = 0; r < 4; ++r)
            ex[(w * 32 + m * 16 + khi * 4 + r) * 64 + n * 16 + l15] = acc[m][n][r];
      __syncthreads();

      // elementwise LSTM update (combine 4 wave partials + bias)
      {
        unsigned short* hd = h0buf + ((size_t)((par ^ 1) * BATCH + eb) << 10);
        float hv0, hv1;
#pragma unroll
        for (int jj = 0; jj < 2; ++jj) {
          int u = euu + jj;
          float gs[4];
#pragma unroll
          for (int n = 0; n < 4; ++n) {
            float ssum = 0.f;
#pragma unroll
            for (int ww = 0; ww < 4; ++ww) ssum += ex[(ww * 32 + erow) * 64 + n * 16 + u];
            int grow = n * 1024 + u0 + u;
            gs[n] = ssum + pB0a[grow] + pB0b[grow];
          }
          float cv = jj ? c0reg1 : c0reg0;
          float cn = sigm(gs[1]) * cv + sigm(gs[0]) * tanh_f(gs[2]);
          if (jj) c0reg1 = cn; else c0reg0 = cn;
          float hn = sigm(gs[3]) * tanh_f(cn);
          if (jj) hv1 = hn; else hv0 = hn;
        }
        int uswz = (u0 + euu) ^ ((erow & 7) << 3);   // pre-swizzled global store
        unsigned pk = (unsigned)f2bf(hv0) | ((unsigned)f2bf(hv1) << 16);
        *(unsigned*)(hd + uswz) = pk;
      }
      // arrive barrier-1 (h0[par^1] published)
      __syncthreads();
      if (tid == 0) {
        __threadfence();
        unsigned prev = __hip_atomic_fetch_add(cnt1, 1u, __ATOMIC_RELEASE, __HIP_MEMORY_SCOPE_AGENT);
        if (prev == (unsigned)(s * 64 + 63))
          __hip_atomic_store(rel1, (unsigned)(s + 1), __ATOMIC_RELEASE, __HIP_MEMORY_SCOPE_AGENT);
      }
    }

    // ===================== LAYER 1 sub-step =====================
    {
      // deferred wait on barrier-2 of previous step (hidden under whole L0 sub-step)
      if (s > 0) {
        if (tid == 0) {
          while (__hip_atomic_load(rel2, __ATOMIC_ACQUIRE, __HIP_MEMORY_SCOPE_AGENT) < (unsigned)s)
            __builtin_amdgcn_s_sleep(4);
          __threadfence();   // acquire: invalidate L1
        }
      }
      __syncthreads();

      // stage upper K half: h1[par] -> A1 cols [1024,2048)
#pragma unroll
      for (int rr = 0; rr < 8; ++rr) {
        int row = w * 8 + rr;
        const char* src = (const char*)(h1buf + ((size_t)(par * BATCH + r0 + row) << 10));
        char* dst = smem + row * PITCH1 + 2048;
        glds16(src + lane * 16, dst);
        glds16(src + 1024 + lane * 16, dst + 1024);
      }
      asm volatile("s_waitcnt vmcnt(0)" ::: "memory");
      __syncthreads();

      f32x4 acc[2][4];
#pragma unroll
      for (int m = 0; m < 2; ++m)
#pragma unroll
        for (int n = 0; n < 4; ++n) acc[m][n] = {0.f, 0.f, 0.f, 0.f};

      // upper-half MFMA (Whh1 x h1) while waiting on barrier-1
#pragma unroll
      for (int j = 8; j < 16; ++j) {
        int off = (w + 4 * j) << 6;
#pragma unroll
        for (int m = 0; m < 2; ++m) {
          const s16x8 af = *(const s16x8*)(smem + (m * 16 + l15) * PITCH1 + ((off + khi * 16) ^ key));
#pragma unroll
          for (int n = 0; n < 4; ++n)
            acc[m][n] = __builtin_amdgcn_mfma_f32_16x16x32_bf16(af, wfb[j][n], acc[m][n], 0, 0, 0);
        }
      }
      // wait barrier-1 (h0[par^1] from all unit-tiles of this batch group)
      if (tid == 0) {
        while (__hip_atomic_load(rel1, __ATOMIC_ACQUIRE, __HIP_MEMORY_SCOPE_AGENT) < (unsigned)(s + 1))
          __builtin_amdgcn_s_sleep(4);
        __threadfence();
      }
      __syncthreads();

      // stage lower K half: h0[par^1] -> A1 cols [0,1024)
#pragma unroll
      for (int rr = 0; rr < 8; ++rr) {
        int row = w * 8 + rr;
        const char* src = (const char*)(h0buf + ((size_t)((par ^ 1) * BATCH + r0 + row) << 10));
        char* dst = smem + row * PITCH1;
        glds16(src + lane * 16, dst);
        glds16(src + 1024 + lane * 16, dst + 1024);
      }
      asm volatile("s_waitcnt vmcnt(0)" ::: "memory");
      __syncthreads();

#pragma unroll
      for (int j = 0; j < 8; ++j) {
        int off = (w + 4 * j) << 6;
#pragma unroll
        for (int m = 0; m < 2; ++m) {
          const s16x8 af = *(const s16x8*)(smem + (m * 16 + l15) * PITCH1 + ((off + khi * 16) ^ key));
#pragma unroll
          for (int n = 0; n < 4; ++n)
            acc[m][n] = __builtin_amdgcn_mfma_f32_16x16x32_bf16(af, wfb[j][n], acc[m][n], 0, 0, 0);
        }
      }
      __syncthreads();
#pragma unroll
      for (int m = 0; m < 2; ++m)
#pragma unroll
        for (int n = 0; n < 4; ++n)
#pragma unroll
          for (int r = 0; r < 4; ++r)
            ex[(w * 32 + m * 16 + khi * 4 + r) * 64 + n * 16 + l15] = acc[m][n][r];
      __syncthreads();

      // elementwise LSTM update + (decoder) mu/sigma partial reduction
      {
        unsigned short* hd = h1buf + ((size_t)((par ^ 1) * BATCH + eb) << 10);
        float hv0, hv1;
#pragma unroll
        for (int jj = 0; jj < 2; ++jj) {
          int u = euu + jj;
          float gs[4];
#pragma unroll
          for (int n = 0; n < 4; ++n) {
            float ssum = 0.f;
#pragma unroll
            for (int ww = 0; ww < 4; ++ww) ssum += ex[(ww * 32 + erow) * 64 + n * 16 + u];
            int grow = n * 1024 + u0 + u;
            gs[n] = ssum + pB1a[grow] + pB1b[grow];
          }
          float cv = jj ? c1reg1 : c1reg0;
          float cn = sigm(gs[1]) * cv + sigm(gs[0]) * tanh_f(gs[2]);
          if (jj) c1reg1 = cn; else c1reg0 = cn;
          float hn = sigm(gs[3]) * tanh_f(cn);
          if (jj) hv1 = hn; else hv0 = hn;
        }
        int uswz = (u0 + euu) ^ ((erow & 7) << 3);
        unsigned pk = (unsigned)f2bf(hv0) | ((unsigned)f2bf(hv1) << 16);
        *(unsigned*)(hd + uswz) = pk;

        if (!enc) {
          float sm = hv0 * Wmu[u0 + euu] + hv1 * Wmu[u0 + euu + 1];
          float sg = hv0 * Wsig[u0 + euu] + hv1 * Wsig[u0 + euu + 1];
#pragma unroll
          for (int o = 1; o < 8; o <<= 1) { sm += __shfl_xor(sm, o); sg += __shfl_xor(sg, o); }
          if ((tid & 7) == 0) {
            atomicAdd(mu_acc + t * BATCH + eb, sm);
            atomicAdd(sig_acc + t * BATCH + eb, sg);
          }
        }
      }
      // arrive barrier-2 (h1[par^1] published); wait deferred into next step
      __syncthreads();
      if (tid == 0) {
        __threadfence();
        unsigned prev = __hip_atomic_fetch_add(cnt2, 1u, __ATOMIC_RELEASE, __HIP_MEMORY_SCOPE_AGENT);
        if (prev == (unsigned)(s * 64 + 63))
          __hip_atomic_store(rel2, (unsigned)(s + 1), __ATOMIC_RELEASE, __HIP_MEMORY_SCOPE_AGENT);
      }
    }
  }
}

// ---------------- epilogue: bias + softplus ----------------
__global__ void finalize_k(const float* __restrict__ mu_acc, const float* __restrict__ sig_acc,
                           const float* __restrict__ bmu, const float* __restrict__ bsig,
                           float* __restrict__ out) {
  int i = blockIdx.x * 256 + threadIdx.x;
  if (i >= 16384) return;
  int b = i >> 7, t = i & 127;
  float m = mu_acc[t * 128 + b] + bmu[0];
  float sv = sig_acc[t * 128 + b] + bsig[0];
  float sp = sv > 20.f ? sv : log1pf(__expf(sv));
  out[16384 + i] = m;     // mu,  flat [b][t][1]
  out[32768 + i] = sp;    // sigma
}

extern "C" void kernel_launch(void* const* d_in, const int* in_sizes, int n_in,
                              void* d_out, int out_size, void* d_ws, size_t ws_size,
                              hipStream_t stream) {
  const float* x    = (const float*)d_in[0];
  const float* y    = (const float*)d_in[1];
  const float* eWx0 = (const float*)d_in[2];
  const float* eWh0 = (const float*)d_in[3];
  const float* eB0a = (const float*)d_in[4];
  const float* eB0b = (const float*)d_in[5];
  const float* eWx1 = (const float*)d_in[6];
  const float* eWh1 = (const float*)d_in[7];
  const float* eB1a = (const float*)d_in[8];
  const float* eB1b = (const float*)d_in[9];
  const float* dWx0 = (const float*)d_in[10];
  const float* dWh0 = (const float*)d_in[11];
  const float* dB0a = (const float*)d_in[12];
  const float* dB0b = (const float*)d_in[13];
  const float* dWx1 = (const float*)d_in[14];
  const float* dWh1 = (const float*)d_in[15];
  const float* dB1a = (const float*)d_in[16];
  const float* dB1b = (const float*)d_in[17];
  const float* Wmu  = (const float*)d_in[18];
  const float* bmu  = (const float*)d_in[19];
  const float* Wsig = (const float*)d_in[20];
  const float* bsig = (const float*)d_in[21];

  char* ws = (char*)d_ws;
  unsigned short* xbf = (unsigned short*)(ws + OFF_XBF);
  unsigned short* ybf = (unsigned short*)(ws + OFF_YBF);
  unsigned short* h0b = (unsigned short*)(ws + OFF_H0);
  unsigned short* h1b = (unsigned short*)(ws + OFF_H1);
  float* mu_acc  = (float*)(ws + OFF_MU);
  float* sig_acc = (float*)(ws + OFF_SIG);
  unsigned* bars = (unsigned*)(ws + OFF_BAR);

  // zero: h state, mu/sig accumulators, barrier counters; zero output_collection
  hipMemsetAsync(ws + OFF_H0, 0, WS_END - OFF_H0, stream);
  hipMemsetAsync(d_out, 0, (size_t)16384 * 4, stream);

  cvt_inputs<<<1024, 256, 0, stream>>>(x, y, xbf, ybf);
  lstm_main<<<256, 256, 0, stream>>>(eWx0, eWh0, eB0a, eB0b, eWx1, eWh1, eB1a, eB1b,
                                     dWx0, dWh0, dB0a, dB0b, dWx1, dWh1, dB1a, dB1b,
                                     Wmu, Wsig, xbf, ybf, h0b, h1b, mu_acc, sig_acc, bars);
  finalize_k<<<64, 256, 0, stream>>>(mu_acc, sig_acc, bmu, bsig, (float*)d_out);
}

// Round 3
// 5242.189 us; speedup vs baseline: 3.0775x; 3.0775x over previous
//
#include <hip/hip_runtime.h>
#include <stdint.h>

// ---------------- problem constants ----------------
#define BATCH  128
#define TENC   256
#define TDEC   128
#define NSTEPS 384      // 256 encoder + 128 decoder timesteps
#define GP     2176     // G tile pitch bytes (h0 cols 0..2047 + 128B x/y XOR window)
#define HP     2048     // H tile pitch bytes (h1 cols)
#define HOFF   69632    // G = 32*2176 bytes, H starts here
#define SMEMSZ 135168   // 69632 + 32*2048
#define EXP    65       // exchange pitch in f32 words
#define MUSOFF 106496   // muS[8][64] f32 (2KB), overlays H rows 18-19 (dead at use time)

typedef __attribute__((ext_vector_type(8))) short s16x8;
typedef __attribute__((ext_vector_type(4))) float f32x4;

// ---------------- workspace layout (bytes) ----------------
#define OFF_XBF 0u         // x bf16 [128][256][8]       512 KB
#define OFF_YBF 524288u    // y bf16 [128][128]           32 KB
#define OFF_H0  557056u    // h0 [2 par][128][1024] bf16, u-swizzled  512 KB
#define OFF_H1  1081344u   // h1 same                                 512 KB
#define OFF_MU  1605632u   // mu  accum [128 t][128 b] f32             64 KB
#define OFF_SIG 1671168u   // sig accum                                64 KB
#define OFF_BAR 1736704u   // flags: [4 btile][2][64] u32               2 KB
#define WS_END  1738752u

__device__ __forceinline__ unsigned short f2bf(float f) {   // f32 -> bf16 RNE
  unsigned u = __float_as_uint(f);
  u = u + 0x7fffu + ((u >> 16) & 1u);
  return (unsigned short)(u >> 16);
}
__device__ __forceinline__ float sigm(float x) { return 1.f / (1.f + __expf(-x)); }
__device__ __forceinline__ float tanh_f(float x) {
  float a = fabsf(x);
  float e = __expf(-2.f * a);
  float t = (1.f - e) / (1.f + e);
  return x < 0.f ? -t : t;
}

// async global->LDS 16B/lane, COHERENT (sc0|sc1 = CPol 17): bypass stale L1/L2
__device__ __forceinline__ void glds16c(const void* g, void* l) {
  __builtin_amdgcn_global_load_lds((const __attribute__((address_space(1))) void*)g,
                                   (__attribute__((address_space(3))) void*)l, 16, 0, 17);
}
__device__ __forceinline__ unsigned ldcoh(const unsigned* p) {
  unsigned v;
  asm volatile("global_load_dword %0, %1, off sc0 sc1\n\ts_waitcnt vmcnt(0)"
               : "=v"(v) : "v"(p) : "memory");
  return v;
}
__device__ __forceinline__ void stcoh(unsigned* p, unsigned v) {
  asm volatile("global_store_dword %0, %1, off sc0 sc1" :: "v"(p), "v"(v) : "memory");
}

#define BARRIER() do { __builtin_amdgcn_s_barrier(); asm volatile("" ::: "memory"); } while (0)
#define WAIT_LGKM() asm volatile("s_waitcnt lgkmcnt(0)" ::: "memory")
#define WAIT_VM()   asm volatile("s_waitcnt vmcnt(0)" ::: "memory")
#define WAIT_BOTH() asm volatile("s_waitcnt vmcnt(0) lgkmcnt(0)" ::: "memory")

// -------- resident-weight loader (bf16 MFMA B-frags, K-split stride-4 over waves) --------
__device__ __forceinline__ void load_weights(
    s16x8 (&wfa)[9][4], s16x8 (&wfb)[16][4],
    int w, int u0, int l15, int khi,
    const float* W0h, const float* W0x, int xk,
    const float* W1x, const float* W1h) {
#pragma unroll
  for (int j = 0; j < 9; ++j) {
    int kst = w + 4 * j;
#pragma unroll
    for (int n = 0; n < 4; ++n) {
      int g = n * 1024 + u0 + l15;
      s16x8 v;
#pragma unroll
      for (int e = 0; e < 8; ++e) ((unsigned short*)&v)[e] = 0;
      if (kst < 32) {
        const float* p = W0h + (size_t)g * 1024 + kst * 32 + khi * 8;
#pragma unroll
        for (int e = 0; e < 8; ++e) ((unsigned short*)&v)[e] = f2bf(p[e]);
      } else if (kst == 32) {
        if (khi == 0) {
#pragma unroll
          for (int e = 0; e < 8; ++e)
            if (e < xk) ((unsigned short*)&v)[e] = f2bf(W0x[(size_t)g * xk + e]);
        }
      }
      wfa[j][n] = v;
    }
  }
#pragma unroll
  for (int j = 0; j < 16; ++j) {
    int kst = w + 4 * j;
#pragma unroll
    for (int n = 0; n < 4; ++n) {
      int g = n * 1024 + u0 + l15;
      const float* p = (kst < 32)
          ? (W1x + (size_t)g * 1024 + kst * 32 + khi * 8)
          : (W1h + (size_t)g * 1024 + (kst - 32) * 32 + khi * 8);
      s16x8 v;
#pragma unroll
      for (int e = 0; e < 8; ++e) ((unsigned short*)&v)[e] = f2bf(p[e]);
      wfb[j][n] = v;
    }
  }
}

// ---------------- input conversion ----------------
__global__ void cvt_inputs(const float* __restrict__ x, const float* __restrict__ y,
                           unsigned short* __restrict__ xbf, unsigned short* __restrict__ ybf) {
  int i = blockIdx.x * 256 + threadIdx.x;
  if (i < 262144) xbf[i] = f2bf(x[i]);
  if (i < 16384) {
    int b = i >> 7, t = i & 127;
    ybf[i] = f2bf(y[b * 129 + t]);
  }
}

// ---------------- main persistent kernel ----------------
__global__ void __launch_bounds__(256, 1) lstm_main(
    const float* __restrict__ eWx0, const float* __restrict__ eWh0,
    const float* __restrict__ eB0a, const float* __restrict__ eB0b,
    const float* __restrict__ eWx1, const float* __restrict__ eWh1,
    const float* __restrict__ eB1a, const float* __restrict__ eB1b,
    const float* __restrict__ dWx0, const float* __restrict__ dWh0,
    const float* __restrict__ dB0a, const float* __restrict__ dB0b,
    const float* __restrict__ dWx1, const float* __restrict__ dWh1,
    const float* __restrict__ dB1a, const float* __restrict__ dB1b,
    const float* __restrict__ Wmu, const float* __restrict__ Wsig,
    const unsigned short* __restrict__ xbf, const unsigned short* __restrict__ ybf,
    unsigned short* h0buf, unsigned short* h1buf,
    float* mu_acc, float* sig_acc, unsigned* bars) {
  __shared__ char smem[SMEMSZ];

  const int tid = threadIdx.x;
  const int wg = blockIdx.x;
  const int w = tid >> 6;
  const int lane = tid & 63;
  const int l15 = lane & 15;
  const int khi = lane >> 4;
  const int btile = wg & 3;        // sync group
  const int utile = wg >> 2;       // 0..63 -> 16 hidden units
  const int u0 = utile << 4;
  const int r0 = btile << 5;       // 32 batch rows
  const int key = (l15 & 7) << 4;  // XOR bank swizzle

  unsigned* f1 = bars + btile * 128;
  unsigned* f2 = f1 + 64;

  const int erow = tid & 31;
  const int uslot = tid >> 5;

  s16x8 wfa[9][4];
  s16x8 wfb[16][4];
  load_weights(wfa, wfb, w, u0, l15, khi, eWh0, eWx0, 8, eWx1, eWh1);

  float b0s[2][4], b1s[2][4];
#pragma unroll
  for (int jj = 0; jj < 2; ++jj) {
    int u = u0 + uslot * 2 + jj;
#pragma unroll
    for (int n = 0; n < 4; ++n) {
      b0s[jj][n] = eB0a[n * 1024 + u] + eB0b[n * 1024 + u];
      b1s[jj][n] = eB1a[n * 1024 + u] + eB1b[n * 1024 + u];
    }
  }
  const float wm0 = Wmu[u0 + uslot * 2], wm1 = Wmu[u0 + uslot * 2 + 1];
  const float wg0 = Wsig[u0 + uslot * 2], wg1 = Wsig[u0 + uslot * 2 + 1];

  float c0a = 0.f, c0b = 0.f, c1a = 0.f, c1b = 0.f;

  // pre-loop: zero the G tile (h0[par=0] is zero, plus the x XOR windows)
  {
    s16x8 z;
#pragma unroll
    for (int e = 0; e < 8; ++e) ((unsigned short*)&z)[e] = 0;
    for (int o = tid * 16; o < HOFF; o += 4096) *(s16x8*)(smem + o) = z;
  }
  __syncthreads();

  for (int s = 0; s < NSTEPS; ++s) {
    const int enc = (s < 256) ? 1 : 0;
    const int t = enc ? s : (s - 256);
    const int par = s & 1;

    // ===== L0 ===== (a) deferred bar2(s-1) wait
    if (s > 0) {
      for (;;) { unsigned v = ldcoh(f2 + lane); if (__all((int)v >= s)) break; }
      BARRIER();
    }
    // (b) early H-stage: h1[par] -> H (in flight across all of L0)
#pragma unroll
    for (int rr = 0; rr < 8; ++rr) {
      int row = w * 8 + rr;
      const char* src = (const char*)(h1buf + (((size_t)par * BATCH + r0 + row) << 10));
      char* dst = smem + HOFF + row * HP;
      glds16c(src + lane * 16, dst);
      glds16c(src + 1024 + lane * 16, dst + 1024);
    }
    // (c) encoder -> decoder weight/bias swap
    if (s == 256) {
      load_weights(wfa, wfb, w, u0, l15, khi, dWh0, dWx0, 1, dWx1, dWh1);
#pragma unroll
      for (int jj = 0; jj < 2; ++jj) {
        int u = u0 + uslot * 2 + jj;
#pragma unroll
        for (int n = 0; n < 4; ++n) {
          b0s[jj][n] = dB0a[n * 1024 + u] + dB0b[n * 1024 + u];
          b1s[jj][n] = dB1a[n * 1024 + u] + dB1b[n * 1024 + u];
        }
      }
    }
    // (d) x/y slot write into G's XOR window.
    // CRITICAL: re-zero the FULL 128B window every step — the (f) exG overlay of the
    // previous step leaves f32 bytes here; bf16-reinterpreted they can be NaN, and
    // MFMA 0*NaN = NaN even against zero weight frags.  (Round-2 NaN root cause.)
    if (tid < 32) {
      char* wb = smem + tid * GP + 2048;
      s16x8 z;
#pragma unroll
      for (int e = 0; e < 8; ++e) ((unsigned short*)&z)[e] = 0;
#pragma unroll
      for (int q = 0; q < 8; ++q) *(s16x8*)(wb + q * 16) = z;
      int slot = (tid & 7) << 4;
      if (enc) {
        *(s16x8*)(wb + slot) = *(const s16x8*)(xbf + (((size_t)(r0 + tid) * TENC + t) << 3));
      } else {
        s16x8 yv = z;
        ((unsigned short*)&yv)[0] = ybf[(r0 + tid) * TDEC + t];
        *(s16x8*)(wb + slot) = yv;
      }
    }
    WAIT_LGKM();
    BARRIER();
    // (e) L0 MFMA over G (h0 staged by L1(s-1); reused — no restage)
    f32x4 acc[2][4];
#pragma unroll
    for (int m = 0; m < 2; ++m)
#pragma unroll
      for (int n = 0; n < 4; ++n) acc[m][n] = {0.f, 0.f, 0.f, 0.f};
#pragma unroll
    for (int j = 0; j < 8; ++j) {
      int off = (w + 4 * j) << 6;
#pragma unroll
      for (int m = 0; m < 2; ++m) {
        const s16x8 af = *(const s16x8*)(smem + (m * 16 + l15) * GP + ((off + khi * 16) ^ key));
#pragma unroll
        for (int n = 0; n < 4; ++n)
          acc[m][n] = __builtin_amdgcn_mfma_f32_16x16x32_bf16(af, wfa[j][n], acc[m][n], 0, 0, 0);
      }
    }
    if (w == 0) {   // x/y K-slot (kst=32)
#pragma unroll
      for (int m = 0; m < 2; ++m) {
        const s16x8 af = *(const s16x8*)(smem + (m * 16 + l15) * GP + ((2048 + khi * 16) ^ key));
#pragma unroll
        for (int n = 0; n < 4; ++n)
          acc[m][n] = __builtin_amdgcn_mfma_f32_16x16x32_bf16(af, wfa[8][n], acc[m][n], 0, 0, 0);
      }
    }
    WAIT_LGKM();
    BARRIER();
    // (f) exchange partials -> exG (overlays dead G h0 cols)
    {
      float* exw = (float*)smem;
#pragma unroll
      for (int m = 0; m < 2; ++m)
#pragma unroll
        for (int n = 0; n < 4; ++n)
#pragma unroll
          for (int r = 0; r < 4; ++r)
            exw[(w * 32 + m * 16 + khi * 4 + r) * EXP + n * 16 + l15] = acc[m][n][r];
    }
    WAIT_LGKM();
    BARRIER();
    // (g) elementwise L0, coherent h0 store
    {
      const float* exw = (const float*)smem;
      unsigned short* hb = h0buf + (((size_t)(par ^ 1) * BATCH + r0 + erow) << 10);
      float hv[2];
#pragma unroll
      for (int jj = 0; jj < 2; ++jj) {
        int u = uslot * 2 + jj;
        float g[4];
#pragma unroll
        for (int n = 0; n < 4; ++n) {
          int c = n * 16 + u;
          g[n] = exw[erow * EXP + c] + exw[(32 + erow) * EXP + c]
               + exw[(64 + erow) * EXP + c] + exw[(96 + erow) * EXP + c] + b0s[jj][n];
        }
        float cv = jj ? c0b : c0a;
        float cn = sigm(g[1]) * cv + sigm(g[0]) * tanh_f(g[2]);
        if (jj) c0b = cn; else c0a = cn;
        hv[jj] = sigm(g[3]) * tanh_f(cn);
      }
      int uswz = (u0 + uslot * 2) ^ ((erow & 7) << 3);
      unsigned pk = (unsigned)f2bf(hv[0]) | ((unsigned)f2bf(hv[1]) << 16);
      stcoh((unsigned*)(hb + uswz), pk);
    }
    WAIT_VM();      // h0 stores committed; H-stage glds also complete by here
    BARRIER();
    if (tid == 0) stcoh(f1 + utile, (unsigned)(s + 1));

    // ===== L1 ===== (h) upper MFMA part A on H (h1 x Whh1)
    f32x4 bcc[2][4];
#pragma unroll
    for (int m = 0; m < 2; ++m)
#pragma unroll
      for (int n = 0; n < 4; ++n) bcc[m][n] = {0.f, 0.f, 0.f, 0.f};
#pragma unroll
    for (int j = 8; j < 11; ++j) {
      int off = (w + 4 * (j - 8)) << 6;
#pragma unroll
      for (int m = 0; m < 2; ++m) {
        const s16x8 af = *(const s16x8*)(smem + HOFF + (m * 16 + l15) * HP + ((off + khi * 16) ^ key));
#pragma unroll
        for (int n = 0; n < 4; ++n)
          bcc[m][n] = __builtin_amdgcn_mfma_f32_16x16x32_bf16(af, wfb[j][n], bcc[m][n], 0, 0, 0);
      }
    }
    // (i) wait bar1(s)
    for (;;) { unsigned v = ldcoh(f1 + lane); if (__all((int)v >= s + 1)) break; }
    // (j) G-stage: h0[par^1] -> G (coherent)
#pragma unroll
    for (int rr = 0; rr < 8; ++rr) {
      int row = w * 8 + rr;
      const char* src = (const char*)(h0buf + (((size_t)(par ^ 1) * BATCH + r0 + row) << 10));
      char* dst = smem + row * GP;
      glds16c(src + lane * 16, dst);
      glds16c(src + 1024 + lane * 16, dst + 1024);
    }
    // (k) upper MFMA part B (hides G-stage latency)
#pragma unroll
    for (int j = 11; j < 16; ++j) {
      int off = (w + 4 * (j - 8)) << 6;
#pragma unroll
      for (int m = 0; m < 2; ++m) {
        const s16x8 af = *(const s16x8*)(smem + HOFF + (m * 16 + l15) * HP + ((off + khi * 16) ^ key));
#pragma unroll
        for (int n = 0; n < 4; ++n)
          bcc[m][n] = __builtin_amdgcn_mfma_f32_16x16x32_bf16(af, wfb[j][n], bcc[m][n], 0, 0, 0);
      }
    }
    WAIT_VM();
    BARRIER();
    // (l) lower MFMA on G (h0 x Wih1)
#pragma unroll
    for (int j = 0; j < 8; ++j) {
      int off = (w + 4 * j) << 6;
#pragma unroll
      for (int m = 0; m < 2; ++m) {
        const s16x8 af = *(const s16x8*)(smem + (m * 16 + l15) * GP + ((off + khi * 16) ^ key));
#pragma unroll
        for (int n = 0; n < 4; ++n)
          bcc[m][n] = __builtin_amdgcn_mfma_f32_16x16x32_bf16(af, wfb[j][n], bcc[m][n], 0, 0, 0);
      }
    }
    WAIT_LGKM();
    BARRIER();
    // (m) exchange partials -> exH (overlays dead H)
    {
      float* exw = (float*)(smem + HOFF);
#pragma unroll
      for (int m = 0; m < 2; ++m)
#pragma unroll
        for (int n = 0; n < 4; ++n)
#pragma unroll
          for (int r = 0; r < 4; ++r)
            exw[(w * 32 + m * 16 + khi * 4 + r) * EXP + n * 16 + l15] = bcc[m][n][r];
    }
    WAIT_LGKM();
    BARRIER();
    // (n) elementwise L1, coherent h1 store, mu/sig partials
    {
      const float* exw = (const float*)(smem + HOFF);
      unsigned short* hb = h1buf + (((size_t)(par ^ 1) * BATCH + r0 + erow) << 10);
      float hv[2];
#pragma unroll
      for (int jj = 0; jj < 2; ++jj) {
        int u = uslot * 2 + jj;
        float g[4];
#pragma unroll
        for (int n = 0; n < 4; ++n) {
          int c = n * 16 + u;
          g[n] = exw[erow * EXP + c] + exw[(32 + erow) * EXP + c]
               + exw[(64 + erow) * EXP + c] + exw[(96 + erow) * EXP + c] + b1s[jj][n];
        }
        float cv = jj ? c1b : c1a;
        float cn = sigm(g[1]) * cv + sigm(g[0]) * tanh_f(g[2]);
        if (jj) c1b = cn; else c1a = cn;
        hv[jj] = sigm(g[3]) * tanh_f(cn);
      }
      int uswz = (u0 + uslot * 2) ^ ((erow & 7) << 3);
      unsigned pk = (unsigned)f2bf(hv[0]) | ((unsigned)f2bf(hv[1]) << 16);
      stcoh((unsigned*)(hb + uswz), pk);
      if (!enc) {
        float* muS = (float*)(smem + MUSOFF);
        muS[uslot * 64 + erow] = hv[0] * wm0 + hv[1] * wm1;
        muS[uslot * 64 + 32 + erow] = hv[0] * wg0 + hv[1] * wg1;
      }
    }
    WAIT_BOTH();
    BARRIER();
    if (tid == 0) stcoh(f2 + utile, (unsigned)(s + 1));
    // (o) mu/sig reduce + fire-and-forget atomics (next H-stage gated by (a)-barrier)
    if (!enc && tid < 64) {
      const float* muS = (const float*)(smem + MUSOFF);
      float sum = 0.f;
#pragma unroll
      for (int q = 0; q < 8; ++q) sum += muS[q * 64 + tid];
      if (tid < 32) atomicAdd(mu_acc + t * BATCH + r0 + tid, sum);
      else          atomicAdd(sig_acc + t * BATCH + r0 + (tid - 32), sum);
    }
  }
}

// ---------------- epilogue: bias + softplus ----------------
__global__ void finalize_k(const float* __restrict__ mu_acc, const float* __restrict__ sig_acc,
                           const float* __restrict__ bmu, const float* __restrict__ bsig,
                           float* __restrict__ out) {
  int i = blockIdx.x * 256 + threadIdx.x;
  if (i >= 16384) return;
  int b = i >> 7, t = i & 127;
  float m = mu_acc[t * 128 + b] + bmu[0];
  float sv = sig_acc[t * 128 + b] + bsig[0];
  float sp = sv > 20.f ? sv : log1pf(__expf(sv));
  out[16384 + i] = m;
  out[32768 + i] = sp;
}

extern "C" void kernel_launch(void* const* d_in, const int* in_sizes, int n_in,
                              void* d_out, int out_size, void* d_ws, size_t ws_size,
                              hipStream_t stream) {
  const float* x    = (const float*)d_in[0];
  const float* y    = (const float*)d_in[1];
  const float* eWx0 = (const float*)d_in[2];
  const float* eWh0 = (const float*)d_in[3];
  const float* eB0a = (const float*)d_in[4];
  const float* eB0b = (const float*)d_in[5];
  const float* eWx1 = (const float*)d_in[6];
  const float* eWh1 = (const float*)d_in[7];
  const float* eB1a = (const float*)d_in[8];
  const float* eB1b = (const float*)d_in[9];
  const float* dWx0 = (const float*)d_in[10];
  const float* dWh0 = (const float*)d_in[11];
  const float* dB0a = (const float*)d_in[12];
  const float* dB0b = (const float*)d_in[13];
  const float* dWx1 = (const float*)d_in[14];
  const float* dWh1 = (const float*)d_in[15];
  const float* dB1a = (const float*)d_in[16];
  const float* dB1b = (const float*)d_in[17];
  const float* Wmu  = (const float*)d_in[18];
  const float* bmu  = (const float*)d_in[19];
  const float* Wsig = (const float*)d_in[20];
  const float* bsig = (const float*)d_in[21];

  char* ws = (char*)d_ws;
  unsigned short* xbf = (unsigned short*)(ws + OFF_XBF);
  unsigned short* ybf = (unsigned short*)(ws + OFF_YBF);
  unsigned short* h0b = (unsigned short*)(ws + OFF_H0);
  unsigned short* h1b = (unsigned short*)(ws + OFF_H1);
  float* mu_acc  = (float*)(ws + OFF_MU);
  float* sig_acc = (float*)(ws + OFF_SIG);
  unsigned* bars = (unsigned*)(ws + OFF_BAR);

  hipMemsetAsync(ws + OFF_H0, 0, WS_END - OFF_H0, stream);
  hipMemsetAsync(d_out, 0, (size_t)16384 * 4, stream);

  cvt_inputs<<<1024, 256, 0, stream>>>(x, y, xbf, ybf);
  lstm_main<<<256, 256, 0, stream>>>(eWx0, eWh0, eB0a, eB0b, eWx1, eWh1, eB1a, eB1b,
                                     dWx0, dWh0, dB0a, dB0b, dWx1, dWh1, dB1a, dB1b,
                                     Wmu, Wsig, xbf, ybf, h0b, h1b, mu_acc, sig_acc, bars);
  finalize_k<<<64, 256, 0, stream>>>(mu_acc, sig_acc, bmu, bsig, (float*)d_out);
}

// Round 4
// 3945.971 us; speedup vs baseline: 4.0884x; 1.3285x over previous
//
#include <hip/hip_runtime.h>
#include <stdint.h>

// ---------------- problem constants ----------------
#define BATCH  128
#define TENC   256
#define TDEC   128
#define NSTEPS 384      // 256 encoder + 128 decoder timesteps
#define GP     2176     // G tile pitch bytes (h0 cols + 128B x/y XOR window)
#define HP     2048     // H tile pitch bytes (h1 cols)
#define HOFF   69632    // G = 32*2176 bytes, H starts here
#define SMEMSZ 135168   // 69632 + 32*2048
#define EXP    65       // exchange pitch in f32 words
#define MUSOFF 106496   // muS[8][64] f32 (2KB) = H rows 18-19 (dead at use time)

typedef __attribute__((ext_vector_type(8))) short s16x8;
typedef __attribute__((ext_vector_type(4))) float f32x4;

// ---------------- workspace layout (bytes) ----------------
#define OFF_XBF 0u         // x bf16 [128][256][8]       512 KB
#define OFF_YBF 524288u    // y bf16 [128][128]           32 KB
#define OFF_H0  557056u    // h0 [2 par][128][1024] bf16, u-swizzled  512 KB
#define OFF_H1  1081344u   // h1 same                                 512 KB
#define OFF_MU  1605632u   // mu  accum [128 t][128 b] f32             64 KB
#define OFF_SIG 1671168u   // sig accum                                64 KB
#define OFF_BAR 1736704u   // counters: [4 group] x 256B                1 KB
#define WS_END  1738752u

__device__ __forceinline__ unsigned short f2bf(float f) {   // f32 -> bf16 RNE
  unsigned u = __float_as_uint(f);
  u = u + 0x7fffu + ((u >> 16) & 1u);
  return (unsigned short)(u >> 16);
}
__device__ __forceinline__ float sigm(float x) { return 1.f / (1.f + __expf(-x)); }
__device__ __forceinline__ float tanh_f(float x) {
  float a = fabsf(x);
  float e = __expf(-2.f * a);
  float t = (1.f - e) / (1.f + e);
  return x < 0.f ? -t : t;
}

// async global->LDS 16B/lane, COHERENT (sc0|sc1 = CPol 17): bypass stale L1/L2
__device__ __forceinline__ void glds16c(const void* g, void* l) {
  __builtin_amdgcn_global_load_lds((const __attribute__((address_space(1))) void*)g,
                                   (__attribute__((address_space(3))) void*)l, 16, 0, 17);
}
__device__ __forceinline__ unsigned ldcoh(const unsigned* p) {
  unsigned v;
  asm volatile("global_load_dword %0, %1, off sc0 sc1\n\ts_waitcnt vmcnt(0)"
               : "=v"(v) : "v"(p) : "memory");
  return v;
}
__device__ __forceinline__ void stcoh(unsigned* p, unsigned v) {
  asm volatile("global_store_dword %0, %1, off sc0 sc1" :: "v"(p), "v"(v) : "memory");
}
// single-address poll: 64 lanes load the SAME dword -> coalesces to 1 L3 request
__device__ __forceinline__ void pollcnt(const unsigned* p, unsigned target) {
  for (;;) {
    unsigned v = ldcoh(p);
    if ((int)v >= (int)target) break;
    __builtin_amdgcn_s_sleep(1);
  }
}

#define BARRIER() do { __builtin_amdgcn_s_barrier(); asm volatile("" ::: "memory"); } while (0)
#define WAIT_LGKM() asm volatile("s_waitcnt lgkmcnt(0)" ::: "memory")
#define WAIT_VM()   asm volatile("s_waitcnt vmcnt(0)" ::: "memory")
#define WAIT_BOTH() asm volatile("s_waitcnt vmcnt(0) lgkmcnt(0)" ::: "memory")

// -------- resident-weight loader (bf16 MFMA B-frags, K-split stride-4 over waves) --------
__device__ __forceinline__ void load_weights(
    s16x8 (&wfa)[9][4], s16x8 (&wfb)[16][4],
    int w, int u0, int l15, int khi,
    const float* W0h, const float* W0x, int xk,
    const float* W1x, const float* W1h) {
#pragma unroll
  for (int j = 0; j < 9; ++j) {
    int kst = w + 4 * j;
#pragma unroll
    for (int n = 0; n < 4; ++n) {
      int g = n * 1024 + u0 + l15;
      s16x8 v;
#pragma unroll
      for (int e = 0; e < 8; ++e) ((unsigned short*)&v)[e] = 0;
      if (kst < 32) {
        const float* p = W0h + (size_t)g * 1024 + kst * 32 + khi * 8;
#pragma unroll
        for (int e = 0; e < 8; ++e) ((unsigned short*)&v)[e] = f2bf(p[e]);
      } else if (kst == 32) {
        if (khi == 0) {
#pragma unroll
          for (int e = 0; e < 8; ++e)
            if (e < xk) ((unsigned short*)&v)[e] = f2bf(W0x[(size_t)g * xk + e]);
        }
      }
      wfa[j][n] = v;
    }
  }
#pragma unroll
  for (int j = 0; j < 16; ++j) {
    int kst = w + 4 * j;
#pragma unroll
    for (int n = 0; n < 4; ++n) {
      int g = n * 1024 + u0 + l15;
      const float* p = (kst < 32)
          ? (W1x + (size_t)g * 1024 + kst * 32 + khi * 8)
          : (W1h + (size_t)g * 1024 + (kst - 32) * 32 + khi * 8);
      s16x8 v;
#pragma unroll
      for (int e = 0; e < 8; ++e) ((unsigned short*)&v)[e] = f2bf(p[e]);
      wfb[j][n] = v;
    }
  }
}

// ---------------- input conversion ----------------
__global__ void cvt_inputs(const float* __restrict__ x, const float* __restrict__ y,
                           unsigned short* __restrict__ xbf, unsigned short* __restrict__ ybf) {
  int i = blockIdx.x * 256 + threadIdx.x;
  if (i < 262144) xbf[i] = f2bf(x[i]);
  if (i < 16384) {
    int b = i >> 7, t = i & 127;
    ybf[i] = f2bf(y[b * 129 + t]);
  }
}

// ---------------- main persistent kernel ----------------
__global__ void __launch_bounds__(256, 1) lstm_main(
    const float* __restrict__ eWx0, const float* __restrict__ eWh0,
    const float* __restrict__ eB0a, const float* __restrict__ eB0b,
    const float* __restrict__ eWx1, const float* __restrict__ eWh1,
    const float* __restrict__ eB1a, const float* __restrict__ eB1b,
    const float* __restrict__ dWx0, const float* __restrict__ dWh0,
    const float* __restrict__ dB0a, const float* __restrict__ dB0b,
    const float* __restrict__ dWx1, const float* __restrict__ dWh1,
    const float* __restrict__ dB1a, const float* __restrict__ dB1b,
    const float* __restrict__ Wmu, const float* __restrict__ Wsig,
    const unsigned short* __restrict__ xbf, const unsigned short* __restrict__ ybf,
    unsigned short* h0buf, unsigned short* h1buf,
    float* mu_acc, float* sig_acc, unsigned* bars) {
  __shared__ char smem[SMEMSZ];

  const int tid = threadIdx.x;
  const int wg = blockIdx.x;
  const int w = tid >> 6;
  const int lane = tid & 63;
  const int l15 = lane & 15;
  const int khi = lane >> 4;
  const int btile = wg & 3;        // sync group
  const int utile = wg >> 2;       // 0..63 -> 16 hidden units
  const int u0 = utile << 4;
  const int r0 = btile << 5;       // 32 batch rows
  const int key = (l15 & 7) << 4;  // XOR bank swizzle

  unsigned* cnt1 = bars + btile * 64;        // 256B per group
  unsigned* cnt2 = cnt1 + 16;                // separate 64B line

  // elementwise partition: erow = tid>>3 (coalesced stores!), uslot = tid&7
  const int erow = tid >> 3;
  const int uslot = tid & 7;

  s16x8 wfa[9][4];
  s16x8 wfb[16][4];
  load_weights(wfa, wfb, w, u0, l15, khi, eWh0, eWx0, 8, eWx1, eWh1);

  float b0s[2][4], b1s[2][4];
#pragma unroll
  for (int jj = 0; jj < 2; ++jj) {
    int u = u0 + uslot * 2 + jj;
#pragma unroll
    for (int n = 0; n < 4; ++n) {
      b0s[jj][n] = eB0a[n * 1024 + u] + eB0b[n * 1024 + u];
      b1s[jj][n] = eB1a[n * 1024 + u] + eB1b[n * 1024 + u];
    }
  }
  const float wm0 = Wmu[u0 + uslot * 2], wm1 = Wmu[u0 + uslot * 2 + 1];
  const float wg0 = Wsig[u0 + uslot * 2], wg1 = Wsig[u0 + uslot * 2 + 1];

  float c0a = 0.f, c0b = 0.f, c1a = 0.f, c1b = 0.f;

  // pre-loop: zero the G tile (h0[par=0] = 0, plus x windows)
  {
    s16x8 z;
#pragma unroll
    for (int e = 0; e < 8; ++e) ((unsigned short*)&z)[e] = 0;
    for (int o = tid * 16; o < HOFF; o += 4096) *(s16x8*)(smem + o) = z;
  }
  __syncthreads();

  for (int s = 0; s < NSTEPS; ++s) {
    const int enc = (s < 256) ? 1 : 0;
    const int t = enc ? s : (s - 256);
    const int par = s & 1;

    // (P1) x/y slot write into G's XOR window (re-zero full 128B window: exG residue!)
    if (tid < 32) {
      char* wb = smem + tid * GP + 2048;
      s16x8 z;
#pragma unroll
      for (int e = 0; e < 8; ++e) ((unsigned short*)&z)[e] = 0;
#pragma unroll
      for (int q = 0; q < 8; ++q) *(s16x8*)(wb + q * 16) = z;
      int slot = (tid & 7) << 4;
      if (enc) {
        *(s16x8*)(wb + slot) = *(const s16x8*)(xbf + (((size_t)(r0 + tid) * TENC + t) << 3));
      } else {
        s16x8 yv = z;
        ((unsigned short*)&yv)[0] = ybf[(r0 + tid) * TDEC + t];
        *(s16x8*)(wb + slot) = yv;
      }
    }
    // (P1b) encoder -> decoder weight/bias swap
    if (s == 256) {
      load_weights(wfa, wfb, w, u0, l15, khi, dWh0, dWx0, 1, dWx1, dWh1);
#pragma unroll
      for (int jj = 0; jj < 2; ++jj) {
        int u = u0 + uslot * 2 + jj;
#pragma unroll
        for (int n = 0; n < 4; ++n) {
          b0s[jj][n] = dB0a[n * 1024 + u] + dB0b[n * 1024 + u];
          b1s[jj][n] = dB1a[n * 1024 + u] + dB1b[n * 1024 + u];
        }
      }
    }
    WAIT_LGKM();
    BARRIER();

    // (P2) L0 MFMA over G — needs NO new cross-WG sync (G staged last step under bar1)
    f32x4 acc[2][4];
#pragma unroll
    for (int m = 0; m < 2; ++m)
#pragma unroll
      for (int n = 0; n < 4; ++n) acc[m][n] = {0.f, 0.f, 0.f, 0.f};
#pragma unroll
    for (int j = 0; j < 8; ++j) {
      int off = (w + 4 * j) << 6;
#pragma unroll
      for (int m = 0; m < 2; ++m) {
        const s16x8 af = *(const s16x8*)(smem + (m * 16 + l15) * GP + ((off + khi * 16) ^ key));
#pragma unroll
        for (int n = 0; n < 4; ++n)
          acc[m][n] = __builtin_amdgcn_mfma_f32_16x16x32_bf16(af, wfa[j][n], acc[m][n], 0, 0, 0);
      }
    }
    if (w == 0) {   // x/y K-slot
#pragma unroll
      for (int m = 0; m < 2; ++m) {
        const s16x8 af = *(const s16x8*)(smem + (m * 16 + l15) * GP + ((2048 + khi * 16) ^ key));
#pragma unroll
        for (int n = 0; n < 4; ++n)
          acc[m][n] = __builtin_amdgcn_mfma_f32_16x16x32_bf16(af, wfa[8][n], acc[m][n], 0, 0, 0);
      }
    }

    // (P3) bar2(s-1) poll (hidden under L0 MFMA epoch) + H-stage h1[par] issue
    pollcnt(cnt2, 64u * (unsigned)s);
#pragma unroll
    for (int rr = 0; rr < 8; ++rr) {
      int row = w * 8 + rr;
      const char* src = (const char*)(h1buf + (((size_t)par * BATCH + r0 + row) << 10));
      char* dst = smem + HOFF + row * HP;
      glds16c(src + lane * 16, dst);
      glds16c(src + 1024 + lane * 16, dst + 1024);
    }

    // (P4) exchange L0 partials -> exG (overlays G rows 0-15)
    WAIT_LGKM();
    BARRIER();            // all waves done reading G
    {
      float* exw = (float*)smem;
#pragma unroll
      for (int m = 0; m < 2; ++m)
#pragma unroll
        for (int n = 0; n < 4; ++n)
#pragma unroll
          for (int r = 0; r < 4; ++r)
            exw[(w * 32 + m * 16 + khi * 4 + r) * EXP + n * 16 + l15] = acc[m][n][r];
    }
    WAIT_LGKM();
    BARRIER();

    // (P5) elementwise L0 + coalesced coherent h0 store
    {
      const float* exw = (const float*)smem;
      unsigned short* hb = h0buf + (((size_t)(par ^ 1) * BATCH + r0 + erow) << 10);
      float hv[2];
#pragma unroll
      for (int jj = 0; jj < 2; ++jj) {
        int u = uslot * 2 + jj;
        float g[4];
#pragma unroll
        for (int n = 0; n < 4; ++n) {
          int c = n * 16 + u;
          g[n] = exw[erow * EXP + c] + exw[(32 + erow) * EXP + c]
               + exw[(64 + erow) * EXP + c] + exw[(96 + erow) * EXP + c] + b0s[jj][n];
        }
        float cv = jj ? c0b : c0a;
        float cn = sigm(g[1]) * cv + sigm(g[0]) * tanh_f(g[2]);
        if (jj) c0b = cn; else c0a = cn;
        hv[jj] = sigm(g[3]) * tanh_f(cn);
      }
      int uswz = (u0 + uslot * 2) ^ ((erow & 7) << 3);
      unsigned pk = (unsigned)f2bf(hv[0]) | ((unsigned)f2bf(hv[1]) << 16);
      stcoh((unsigned*)(hb + uswz), pk);
    }
    WAIT_VM();            // h0 store-acks + H-stage glds complete
    BARRIER();
    if (tid == 0) atomicAdd(cnt1, 1u);

    // (P6) upper MFMA part A on H (h1 x Whh1), j=8..11 — hides bar1 flag propagation
    f32x4 bcc[2][4];
#pragma unroll
    for (int m = 0; m < 2; ++m)
#pragma unroll
      for (int n = 0; n < 4; ++n) bcc[m][n] = {0.f, 0.f, 0.f, 0.f};
#pragma unroll
    for (int j = 8; j < 12; ++j) {
      int off = (w + 4 * (j - 8)) << 6;
#pragma unroll
      for (int m = 0; m < 2; ++m) {
        const s16x8 af = *(const s16x8*)(smem + HOFF + (m * 16 + l15) * HP + ((off + khi * 16) ^ key));
#pragma unroll
        for (int n = 0; n < 4; ++n)
          bcc[m][n] = __builtin_amdgcn_mfma_f32_16x16x32_bf16(af, wfb[j][n], bcc[m][n], 0, 0, 0);
      }
    }
    // (P7) bar1 poll, then G-stage h0[par^1] issue
    pollcnt(cnt1, 64u * (unsigned)(s + 1));
#pragma unroll
    for (int rr = 0; rr < 8; ++rr) {
      int row = w * 8 + rr;
      const char* src = (const char*)(h0buf + (((size_t)(par ^ 1) * BATCH + r0 + row) << 10));
      char* dst = smem + row * GP;
      glds16c(src + lane * 16, dst);
      glds16c(src + 1024 + lane * 16, dst + 1024);
    }
    // (P8) upper MFMA part B, j=12..15 — hides G-stage L3 latency
#pragma unroll
    for (int j = 12; j < 16; ++j) {
      int off = (w + 4 * (j - 8)) << 6;
#pragma unroll
      for (int m = 0; m < 2; ++m) {
        const s16x8 af = *(const s16x8*)(smem + HOFF + (m * 16 + l15) * HP + ((off + khi * 16) ^ key));
#pragma unroll
        for (int n = 0; n < 4; ++n)
          bcc[m][n] = __builtin_amdgcn_mfma_f32_16x16x32_bf16(af, wfb[j][n], bcc[m][n], 0, 0, 0);
      }
    }
    WAIT_VM();
    BARRIER();
    // (P9) lower MFMA on G (h0 x Wih1)
#pragma unroll
    for (int j = 0; j < 8; ++j) {
      int off = (w + 4 * j) << 6;
#pragma unroll
      for (int m = 0; m < 2; ++m) {
        const s16x8 af = *(const s16x8*)(smem + (m * 16 + l15) * GP + ((off + khi * 16) ^ key));
#pragma unroll
        for (int n = 0; n < 4; ++n)
          bcc[m][n] = __builtin_amdgcn_mfma_f32_16x16x32_bf16(af, wfb[j][n], bcc[m][n], 0, 0, 0);
      }
    }
    WAIT_LGKM();
    BARRIER();
    // (P10) exchange L1 partials -> exH (overlays H rows 0-16)
    {
      float* exw = (float*)(smem + HOFF);
#pragma unroll
      for (int m = 0; m < 2; ++m)
#pragma unroll
        for (int n = 0; n < 4; ++n)
#pragma unroll
          for (int r = 0; r < 4; ++r)
            exw[(w * 32 + m * 16 + khi * 4 + r) * EXP + n * 16 + l15] = bcc[m][n][r];
    }
    WAIT_LGKM();
    BARRIER();
    // (P11) elementwise L1 + coalesced coherent h1 store + muS partials
    {
      const float* exw = (const float*)(smem + HOFF);
      unsigned short* hb = h1buf + (((size_t)(par ^ 1) * BATCH + r0 + erow) << 10);
      float hv[2];
#pragma unroll
      for (int jj = 0; jj < 2; ++jj) {
        int u = uslot * 2 + jj;
        float g[4];
#pragma unroll
        for (int n = 0; n < 4; ++n) {
          int c = n * 16 + u;
          g[n] = exw[erow * EXP + c] + exw[(32 + erow) * EXP + c]
               + exw[(64 + erow) * EXP + c] + exw[(96 + erow) * EXP + c] + b1s[jj][n];
        }
        float cv = jj ? c1b : c1a;
        float cn = sigm(g[1]) * cv + sigm(g[0]) * tanh_f(g[2]);
        if (jj) c1b = cn; else c1a = cn;
        hv[jj] = sigm(g[3]) * tanh_f(cn);
      }
      int uswz = (u0 + uslot * 2) ^ ((erow & 7) << 3);
      unsigned pk = (unsigned)f2bf(hv[0]) | ((unsigned)f2bf(hv[1]) << 16);
      stcoh((unsigned*)(hb + uswz), pk);
      if (!enc) {
        float* muS = (float*)(smem + MUSOFF);
        muS[uslot * 64 + erow] = hv[0] * wm0 + hv[1] * wm1;
        muS[uslot * 64 + 32 + erow] = hv[0] * wg0 + hv[1] * wg1;
      }
    }
    WAIT_BOTH();
    BARRIER();
    if (tid == 0) atomicAdd(cnt2, 1u);
    // (P12) muS reduce + fire-and-forget atomics (wave 0; gated from next H-stage by P1 barrier)
    if (!enc && tid < 64) {
      const float* muS = (const float*)(smem + MUSOFF);
      float sum = 0.f;
#pragma unroll
      for (int q = 0; q < 8; ++q) sum += muS[q * 64 + tid];
      if (tid < 32) atomicAdd(mu_acc + t * BATCH + r0 + tid, sum);
      else          atomicAdd(sig_acc + t * BATCH + r0 + (tid - 32), sum);
    }
  }
}

// ---------------- epilogue: bias + softplus ----------------
__global__ void finalize_k(const float* __restrict__ mu_acc, const float* __restrict__ sig_acc,
                           const float* __restrict__ bmu, const float* __restrict__ bsig,
                           float* __restrict__ out) {
  int i = blockIdx.x * 256 + threadIdx.x;
  if (i >= 16384) return;
  int b = i >> 7, t = i & 127;
  float m = mu_acc[t * 128 + b] + bmu[0];
  float sv = sig_acc[t * 128 + b] + bsig[0];
  float sp = sv > 20.f ? sv : log1pf(__expf(sv));
  out[16384 + i] = m;
  out[32768 + i] = sp;
}

extern "C" void kernel_launch(void* const* d_in, const int* in_sizes, int n_in,
                              void* d_out, int out_size, void* d_ws, size_t ws_size,
                              hipStream_t stream) {
  const float* x    = (const float*)d_in[0];
  const float* y    = (const float*)d_in[1];
  const float* eWx0 = (const float*)d_in[2];
  const float* eWh0 = (const float*)d_in[3];
  const float* eB0a = (const float*)d_in[4];
  const float* eB0b = (const float*)d_in[5];
  const float* eWx1 = (const float*)d_in[6];
  const float* eWh1 = (const float*)d_in[7];
  const float* eB1a = (const float*)d_in[8];
  const float* eB1b = (const float*)d_in[9];
  const float* dWx0 = (const float*)d_in[10];
  const float* dWh0 = (const float*)d_in[11];
  const float* dB0a = (const float*)d_in[12];
  const float* dB0b = (const float*)d_in[13];
  const float* dWx1 = (const float*)d_in[14];
  const float* dWh1 = (const float*)d_in[15];
  const float* dB1a = (const float*)d_in[16];
  const float* dB1b = (const float*)d_in[17];
  const float* Wmu  = (const float*)d_in[18];
  const float* bmu  = (const float*)d_in[19];
  const float* Wsig = (const float*)d_in[20];
  const float* bsig = (const float*)d_in[21];

  char* ws = (char*)d_ws;
  unsigned short* xbf = (unsigned short*)(ws + OFF_XBF);
  unsigned short* ybf = (unsigned short*)(ws + OFF_YBF);
  unsigned short* h0b = (unsigned short*)(ws + OFF_H0);
  unsigned short* h1b = (unsigned short*)(ws + OFF_H1);
  float* mu_acc  = (float*)(ws + OFF_MU);
  float* sig_acc = (float*)(ws + OFF_SIG);
  unsigned* bars = (unsigned*)(ws + OFF_BAR);

  hipMemsetAsync(ws + OFF_H0, 0, WS_END - OFF_H0, stream);
  hipMemsetAsync(d_out, 0, (size_t)16384 * 4, stream);

  cvt_inputs<<<1024, 256, 0, stream>>>(x, y, xbf, ybf);
  lstm_main<<<256, 256, 0, stream>>>(eWx0, eWh0, eB0a, eB0b, eWx1, eWh1, eB1a, eB1b,
                                     dWx0, dWh0, dB0a, dB0b, dWx1, dWh1, dB1a, dB1b,
                                     Wmu, Wsig, xbf, ybf, h0b, h1b, mu_acc, sig_acc, bars);
  finalize_k<<<64, 256, 0, stream>>>(mu_acc, sig_acc, bmu, bsig, (float*)d_out);
}